// Round 15
// baseline (200.718 us; speedup 1.0000x reference)
//
#include <hip/hip_runtime.h>
#include <hip/hip_cooperative_groups.h>

namespace cg = cooperative_groups;

// Shapes fixed by the benchmark's setup_inputs().
constexpr int T_DIM       = 16;
constexpr int TOK         = 16384;
constexpr int E_DIM       = 128;
constexpr int N_NODE_C    = 8192;
constexpr int NUM_NODES_C = 50000;
constexpr int COMP_LEN_C  = 64;
constexpr int MAX_LEN_C   = 782;
constexpr int COMP_DIM_C  = 32;
constexpr float EPS_F     = 1e-5f;

constexpr int D2     = COMP_LEN_C * COMP_DIM_C;       // 2048
constexpr int GRID_C = 512;                            // (t,chunk) blocks
constexpr int BLK_C  = 256;                            // 4 waves
constexpr int PER_T  = 32;                             // chunks per t
constexpr int RPB    = N_NODE_C / PER_T;               // 256 rows per block
constexpr int W_WORDS = NUM_NODES_C * COMP_LEN_C / 4;  // 800,000 u32

// d_ws: W8 (3.2MB) | P partials (4MB). Both fully rewritten where read.
constexpr size_t W8_BYTES = (size_t)NUM_NODES_C * COMP_LEN_C;
constexpr size_t P_OFF    = 3211264;   // 4KB-aligned

struct SharedT {
  float    vtile[RPB][COMP_DIM_C];  // 32KB: pooled LN values (f32)
  unsigned atile[RPB][16];          // 16KB: W-row bytes (4 c's per u32)
  float    red[16];
};

// ---- Phase 2: LN+pool -> vtile, W-gather -> atile, then register-tiled LDS GEMM.
__device__ __forceinline__ void phase2_main(
    SharedT& sh, int bid, const float* __restrict__ x, const float* __restrict__ g1,
    const float* __restrict__ b1, const int* __restrict__ node_idx,
    const unsigned* __restrict__ W32, float* __restrict__ P) {
  const int t = bid >> 5, chunk = bid & 31;
  const int tid  = threadIdx.x;
  const int lane = tid & 63, wave = tid >> 6;
  const int g = lane & 31, half = lane >> 5, sl = lane & 15, sub = lane >> 4;
  const int rbase = chunk * RPB + wave * 64;     // this wave's 64 rows (within t)
  const int* nit = node_idx + (size_t)t * N_NODE_C;
  const float4* xv = reinterpret_cast<const float4*>(x + (size_t)t * TOK * E_DIM);

  const float4 gv = *reinterpret_cast<const float4*>(g1 + g * 4);
  const float4 bv = *reinterpret_cast<const float4*>(b1 + g * 4);
  const float sg = gv.x + gv.y + gv.z + gv.w;
  const float sb = bv.x + bv.y + bv.z + bv.w;

  const int nid_all = nit[rbase + lane];         // 64 node ids, one per lane

  for (int b = 0; b < 4; ++b) {                  // 16 rows per batch
    // W-gather: 4 passes cover 16 rows (row = b*16 + j*4 + sub, word sl).
    int rnid[4]; unsigned w4[4];
#pragma unroll
    for (int j = 0; j < 4; ++j) rnid[j] = __shfl(nid_all, b * 16 + j * 4 + sub);
#pragma unroll
    for (int j = 0; j < 4; ++j) w4[j] = W32[(size_t)rnid[j] * 16 + sl];
    unsigned long long bal[4];
#pragma unroll
    for (int j = 0; j < 4; ++j) bal[j] = __ballot(w4[j] != 0u);
#pragma unroll
    for (int j = 0; j < 4; ++j) sh.atile[wave * 64 + b * 16 + j * 4 + sub][sl] = w4[j];

    // x loads only for alive rows (~63%), all 8 issued back-to-back.
    float4 xd[8];
#pragma unroll
    for (int i = 0; i < 8; ++i) {
      int rloc = 2 * i + half;                   // 0..15 within batch
      bool alive = ((bal[rloc >> 2] >> ((rloc & 3) * 16)) & 0xFFFFull) != 0ull;
      if (alive) xd[i] = xv[(size_t)(rbase + b * 16 + rloc) * 32 + g];
    }
#pragma unroll
    for (int i = 0; i < 8; ++i) {
      int rloc = 2 * i + half;
      bool alive = ((bal[rloc >> 2] >> ((rloc & 3) * 16)) & 0xFFFFull) != 0ull;
      if (alive) {                                // uniform per 32-lane half
        float4 a = xd[i];
        float s = (a.x + a.y) + (a.z + a.w);
        float q = a.x * a.x + a.y * a.y + a.z * a.z + a.w * a.w;
#pragma unroll
        for (int m = 1; m < 32; m <<= 1) { s += __shfl_xor(s, m); q += __shfl_xor(q, m); }
        float mu   = s * (1.0f / E_DIM);
        float var  = q * (1.0f / E_DIM) - mu * mu;
        float rstd = rsqrtf(var + EPS_F);
        float dxg  = a.x * gv.x + a.y * gv.y + a.z * gv.z + a.w * gv.w;
        sh.vtile[wave * 64 + b * 16 + rloc][g] = (dxg - mu * sg) * rstd + sb;
      }
    }
  }
  __syncthreads();

  // Mini-GEMM: thread owns (c = 4*c4..4*c4+3) x (d = 2*d2, 2*d2+1).
  // Dead k's (78% per wave: 16-c span) skipped wave-uniformly. No atomics.
  const int c4 = tid >> 4, d2 = tid & 15;
  float2 acc0{0.f,0.f}, acc1{0.f,0.f}, acc2{0.f,0.f}, acc3{0.f,0.f};
  const float2* vt2 = reinterpret_cast<const float2*>(&sh.vtile[0][0]);
#pragma unroll 4
  for (int k = 0; k < RPB; ++k) {
    unsigned a4 = sh.atile[k][c4];
    if (__ballot(a4 != 0u) != 0ull) {
      float2 v2 = vt2[k * 16 + d2];
      float a0 = (float)(a4 & 255u),         a1 = (float)((a4 >> 8) & 255u);
      float a2 = (float)((a4 >> 16) & 255u), a3 = (float)((a4 >> 24) & 255u);
      acc0.x += a0 * v2.x; acc0.y += a0 * v2.y;
      acc1.x += a1 * v2.x; acc1.y += a1 * v2.y;
      acc2.x += a2 * v2.x; acc2.y += a2 * v2.y;
      acc3.x += a3 * v2.x; acc3.y += a3 * v2.y;
    }
  }
  float2* pr2 = reinterpret_cast<float2*>(P + ((size_t)t * PER_T + chunk) * D2);
  pr2[(c4 * 4 + 0) * 16 + d2] = acc0;
  pr2[(c4 * 4 + 1) * 16 + d2] = acc1;
  pr2[(c4 * 4 + 2) * 16 + d2] = acc2;
  pr2[(c4 * 4 + 3) * 16 + d2] = acc3;
}

// ---- Phase 3: sum 32 partials per t, scale, LN2. (R11-proven)
__device__ __forceinline__ void phase3_final(
    SharedT& sh, int t, const float* __restrict__ P, const float* __restrict__ g2,
    const float* __restrict__ b2, float* __restrict__ out) {
  const float scale = 1.0f / (4.0f * (float)MAX_LEN_C);
  const int tid = threadIdx.x;
  float acc[8] = {0.f,0.f,0.f,0.f,0.f,0.f,0.f,0.f};
  const float* base = P + (size_t)t * PER_T * D2 + tid * 8;
  for (int p = 0; p < PER_T; ++p) {
    float4 v0 = *reinterpret_cast<const float4*>(base + (size_t)p * D2);
    float4 v1 = *reinterpret_cast<const float4*>(base + (size_t)p * D2 + 4);
    acc[0] += v0.x; acc[1] += v0.y; acc[2] += v0.z; acc[3] += v0.w;
    acc[4] += v1.x; acc[5] += v1.y; acc[6] += v1.z; acc[7] += v1.w;
  }
  float y[8]; float s = 0.f, q = 0.f;
#pragma unroll
  for (int k = 0; k < 8; ++k) { float v = acc[k] * scale; y[k] = v; s += v; q += v * v; }
#pragma unroll
  for (int m = 1; m < 64; m <<= 1) { s += __shfl_xor(s, m); q += __shfl_xor(q, m); }
  const int w = tid >> 6, ln = tid & 63;
  if (ln == 0) { sh.red[w] = s; sh.red[8 + w] = q; }
  __syncthreads();
  float ts = sh.red[0] + sh.red[1] + sh.red[2] + sh.red[3];
  float tq = sh.red[8] + sh.red[9] + sh.red[10] + sh.red[11];
  float mu   = ts * (1.0f / D2);
  float var  = tq * (1.0f / D2) - mu * mu;
  float rstd = rsqrtf(var + EPS_F);
#pragma unroll
  for (int k = 0; k < 8; ++k) {
    int idx = tid * 8 + k;
    out[(size_t)t * D2 + idx] = (y[k] - mu) * rstd * g2[idx] + b2[idx];
  }
}

// ---- Cooperative mega-kernel: zeroW -> buildW -> LN/GEMM -> finalLN.
__global__ __launch_bounds__(256, 2) void mega_kernel(
    const float* __restrict__ x, const float* __restrict__ g1, const float* __restrict__ b1,
    const int* __restrict__ node_idx, const int* __restrict__ sidx,
    const float* __restrict__ g2, const float* __restrict__ b2,
    unsigned* __restrict__ W8w, float* __restrict__ P, float* __restrict__ out) {
  cg::grid_group grid = cg::this_grid();
  __shared__ SharedT sh;
  const int gtid = blockIdx.x * BLK_C + threadIdx.x;   // 131072 threads

  for (int i = gtid; i < W_WORDS; i += GRID_C * BLK_C) W8w[i] = 0u;
  grid.sync();
  if (gtid < COMP_LEN_C * MAX_LEN_C) {
    int c = gtid / MAX_LEN_C;
    int n = sidx[gtid];
    int byteoff = n * COMP_LEN_C + c;
    atomicAdd(&W8w[byteoff >> 2], 1u << (8 * (byteoff & 3)));
  }
  grid.sync();
  phase2_main(sh, blockIdx.x, x, g1, b1, node_idx, (const unsigned*)W8w, P);
  grid.sync();
  if (blockIdx.x < T_DIM) phase3_final(sh, blockIdx.x, P, g2, b2, out);
}

// ---- Fallback (non-coop) path.
__global__ void build_w8_kernel(const int* __restrict__ sidx, unsigned* __restrict__ W8w) {
  const int c  = blockIdx.x >> 2;
  const int jc = blockIdx.x & 3;
  const int j  = jc * 196 + threadIdx.x;
  if (j < MAX_LEN_C && threadIdx.x < 196) {
    int n = sidx[c * MAX_LEN_C + j];
    int byteoff = n * COMP_LEN_C + c;
    atomicAdd(&W8w[byteoff >> 2], 1u << (8 * (byteoff & 3)));
  }
}

__global__ __launch_bounds__(256, 2) void main_nc(
    const float* __restrict__ x, const float* __restrict__ g1, const float* __restrict__ b1,
    const int* __restrict__ node_idx, const unsigned* __restrict__ W32,
    float* __restrict__ P) {
  __shared__ SharedT sh;
  phase2_main(sh, blockIdx.x, x, g1, b1, node_idx, W32, P);
}

__global__ __launch_bounds__(256) void final_nc(
    const float* __restrict__ P, const float* __restrict__ g2,
    const float* __restrict__ b2, float* __restrict__ out) {
  __shared__ SharedT sh;
  phase3_final(sh, blockIdx.x, P, g2, b2, out);
}

extern "C" void kernel_launch(void* const* d_in, const int* in_sizes, int n_in,
                              void* d_out, int out_size, void* d_ws, size_t ws_size,
                              hipStream_t stream) {
  const float* x     = (const float*)d_in[0];
  const float* ln1_g = (const float*)d_in[1];
  const float* ln1_b = (const float*)d_in[2];
  const float* ln2_g = (const float*)d_in[3];
  const float* ln2_b = (const float*)d_in[4];
  const int* node_idx = (const int*)d_in[5];
  const int* sidx     = (const int*)d_in[6];
  float* out = (float*)d_out;

  unsigned* W8w = (unsigned*)d_ws;
  float* P = (float*)((unsigned char*)d_ws + P_OFF);

  int maxActive = 0;
  hipError_t occ = hipOccupancyMaxActiveBlocksPerMultiprocessor(
      &maxActive, (const void*)mega_kernel, BLK_C, 0);
  bool coop = (occ == hipSuccess) && (maxActive >= 2);   // 512 blocks on 256 CUs

  if (coop) {
    void* args[] = {(void*)&x, (void*)&ln1_g, (void*)&ln1_b, (void*)&node_idx,
                    (void*)&sidx, (void*)&ln2_g, (void*)&ln2_b,
                    (void*)&W8w, (void*)&P, (void*)&out};
    hipError_t e = hipLaunchCooperativeKernel((void*)mega_kernel, dim3(GRID_C),
                                              dim3(BLK_C), args, 0, stream);
    if (e == hipSuccess) return;
  }

  // Fallback: 4-dispatch pipeline with identical math.
  hipMemsetAsync(W8w, 0, W8_BYTES, stream);
  build_w8_kernel<<<COMP_LEN_C * 4, 256, 0, stream>>>(sidx, W8w);
  main_nc<<<GRID_C, BLK_C, 0, stream>>>(x, ln1_g, ln1_b, node_idx,
                                        (const unsigned*)W8w, P);
  final_nc<<<T_DIM, 256, 0, stream>>>(P, ln2_g, ln2_b, out);
}

// Round 16
// 43.457 us; speedup vs baseline: 4.6188x; 4.6188x over previous
//
#include <hip/hip_runtime.h>
#include <hip/hip_cooperative_groups.h>

namespace cg = cooperative_groups;

constexpr int T_DIM       = 16;
constexpr int TOK         = 16384;
constexpr int E_DIM       = 128;
constexpr int N_NODE_C    = 8192;
constexpr int NUM_NODES_C = 50000;
constexpr int COMP_LEN_C  = 64;
constexpr int MAX_LEN_C   = 782;
constexpr int COMP_DIM_C  = 32;
constexpr float EPS_F     = 1e-5f;

constexpr int D2      = COMP_LEN_C * COMP_DIM_C;        // 2048
constexpr int GRID_C  = 1024;                           // 16 t x 64 chunks, 4/CU
constexpr int BLK_C   = 256;                            // 4 waves
constexpr int PER_T   = 64;
constexpr int RPB     = 128;                            // rows per block
constexpr int W_WORDS = NUM_NODES_C * COMP_LEN_C / 4;   // 800,000

constexpr size_t W8_BYTES = (size_t)NUM_NODES_C * COMP_LEN_C;  // 3.2MB
constexpr size_t P_OFF    = 3211264;                           // P: 16*64*2048*4 = 8.4MB
constexpr size_t AGG_OFF  = P_OFF + (size_t)T_DIM * PER_T * D2 * 4;  // 128KB

struct SharedT {
  float    vtile[RPB][COMP_DIM_C];  // 16KB
  unsigned atile[RPB][16];          // 8KB
  float    red[256];
};

// Phase A+B: dense LN/pool + W-gather -> LDS; branch-free u8 GEMM -> P.
__device__ __forceinline__ void phase_main(
    SharedT& sh, int bid, const float* __restrict__ x, const float* __restrict__ g1,
    const float* __restrict__ b1, const int* __restrict__ node_idx,
    const unsigned* __restrict__ W32, float* __restrict__ P) {
  const int t = bid >> 6, chunk = bid & 63;
  const int tid = threadIdx.x, lane = tid & 63, wave = tid >> 6;
  const int g = lane & 31, half = lane >> 5;
  const int rbase = chunk * RPB;                       // block's 128 rows
  const int* nit = node_idx + (size_t)t * N_NODE_C;
  const float4* xv = reinterpret_cast<const float4*>(x + (size_t)t * TOK * E_DIM);

  // ---- W-gather chain (flat, no ballots): thread covers 8 atile words.
  // word w = tid + j*256 -> row w>>4, word-in-row w&15. nid loads are
  // 16-lane broadcasts; gathers are 64B-coalesced per row.
  int nid8[8];
#pragma unroll
  for (int j = 0; j < 8; ++j) nid8[j] = nit[rbase + ((tid + j * 256) >> 4)];

  // ---- x-stream chain (independent, unconditional, dense). Wave w: rows
  // rbase + w*32 .. +31, as 16 iters of 2 rows; two 8-iter batches.
  const float4 gv = *reinterpret_cast<const float4*>(g1 + g * 4);
  const float4 bv = *reinterpret_cast<const float4*>(b1 + g * 4);
  const float sg = gv.x + gv.y + gv.z + gv.w;
  const float sb = bv.x + bv.y + bv.z + bv.w;
  const int wr0 = rbase + wave * 32;

  float4 xd[8];
#pragma unroll
  for (int i = 0; i < 8; ++i)
    xd[i] = xv[(size_t)(wr0 + 2 * i) * 32 + lane];

  unsigned wg8[8];
#pragma unroll
  for (int j = 0; j < 8; ++j)
    wg8[j] = W32[(size_t)nid8[j] * 16 + ((tid + j * 256) & 15)];

#pragma unroll
  for (int i = 0; i < 8; ++i) {
    const float4 a = xd[i];
    float s = (a.x + a.y) + (a.z + a.w);
    float q = a.x * a.x + a.y * a.y + a.z * a.z + a.w * a.w;
#pragma unroll
    for (int m = 1; m < 32; m <<= 1) { s += __shfl_xor(s, m); q += __shfl_xor(q, m); }
    float mu = s * (1.0f / E_DIM);
    float rstd = rsqrtf(q * (1.0f / E_DIM) - mu * mu + EPS_F);
    float dxg = a.x * gv.x + a.y * gv.y + a.z * gv.z + a.w * gv.w;
    sh.vtile[wave * 32 + 2 * i + half][g] = (dxg - mu * sg) * rstd + sb;
  }
#pragma unroll
  for (int i = 0; i < 8; ++i)
    xd[i] = xv[(size_t)(wr0 + 16 + 2 * i) * 32 + lane];
#pragma unroll
  for (int j = 0; j < 8; ++j) {
    int w = tid + j * 256;
    sh.atile[w >> 4][w & 15] = wg8[j];
  }
#pragma unroll
  for (int i = 0; i < 8; ++i) {
    const float4 a = xd[i];
    float s = (a.x + a.y) + (a.z + a.w);
    float q = a.x * a.x + a.y * a.y + a.z * a.z + a.w * a.w;
#pragma unroll
    for (int m = 1; m < 32; m <<= 1) { s += __shfl_xor(s, m); q += __shfl_xor(q, m); }
    float mu = s * (1.0f / E_DIM);
    float rstd = rsqrtf(q * (1.0f / E_DIM) - mu * mu + EPS_F);
    float dxg = a.x * gv.x + a.y * gv.y + a.z * gv.z + a.w * gv.w;
    sh.vtile[wave * 32 + 16 + 2 * i + half][g] = (dxg - mu * sg) * rstd + sb;
  }
  __syncthreads();

  // ---- Dense branch-free GEMM: thread = (c4 = tid>>4, d2 = tid&15);
  // 4 c's x 2 d's accumulators; k = 0..127, unrolled 4, fully pipelineable.
  const int c4 = tid >> 4, d2 = tid & 15;
  float2 acc0{0,0}, acc1{0,0}, acc2{0,0}, acc3{0,0};
  const float2* vt2 = reinterpret_cast<const float2*>(&sh.vtile[0][0]);
#pragma unroll 4
  for (int k = 0; k < RPB; ++k) {
    unsigned a4 = sh.atile[k][c4];
    float2 v2 = vt2[k * 16 + d2];
    float a0 = (float)(a4 & 255u),         a1 = (float)((a4 >> 8) & 255u);
    float a2 = (float)((a4 >> 16) & 255u), a3 = (float)((a4 >> 24) & 255u);
    acc0.x += a0 * v2.x; acc0.y += a0 * v2.y;
    acc1.x += a1 * v2.x; acc1.y += a1 * v2.y;
    acc2.x += a2 * v2.x; acc2.y += a2 * v2.y;
    acc3.x += a3 * v2.x; acc3.y += a3 * v2.y;
  }
  float2* pr2 = reinterpret_cast<float2*>(P + ((size_t)t * PER_T + chunk) * D2);
  pr2[(c4 * 4 + 0) * 16 + d2] = acc0;
  pr2[(c4 * 4 + 1) * 16 + d2] = acc1;
  pr2[(c4 * 4 + 2) * 16 + d2] = acc2;
  pr2[(c4 * 4 + 3) * 16 + d2] = acc3;
}

// Phase R: 512 blocks reduce P (8.4MB) -> Agg. block=(t,seg); thread sums 16 chunks.
__device__ __forceinline__ void phase_reduce(
    SharedT& sh, int b, const float* __restrict__ P, float* __restrict__ Agg) {
  const int t = b >> 5, seg = b & 31;
  const int tid = threadIdx.x;
  const int elem = seg * 64 + (tid & 63);
  const int q = tid >> 6;
  const float* base = P + (size_t)t * PER_T * D2 + elem;
  float acc = 0.f;
#pragma unroll
  for (int p = 0; p < 16; ++p) acc += base[(size_t)(q * 16 + p) * D2];
  sh.red[tid] = acc;
  __syncthreads();
  if (tid < 64)
    Agg[(size_t)t * D2 + elem] =
        sh.red[tid] + sh.red[tid + 64] + sh.red[tid + 128] + sh.red[tid + 192];
}

// Phase F: final LN2 per t.
__device__ __forceinline__ void phase_final(
    SharedT& sh, int t, const float* __restrict__ Agg, const float* __restrict__ g2,
    const float* __restrict__ b2, float* __restrict__ out) {
  const float scale = 1.0f / (4.0f * (float)MAX_LEN_C);
  const int tid = threadIdx.x;
  float y[8]; float s = 0.f, q = 0.f;
#pragma unroll
  for (int k = 0; k < 8; ++k) {
    float v = Agg[(size_t)t * D2 + tid * 8 + k] * scale;
    y[k] = v; s += v; q += v * v;
  }
#pragma unroll
  for (int m = 1; m < 64; m <<= 1) { s += __shfl_xor(s, m); q += __shfl_xor(q, m); }
  const int w = tid >> 6, ln = tid & 63;
  if (ln == 0) { sh.red[w] = s; sh.red[8 + w] = q; }
  __syncthreads();
  float ts = sh.red[0] + sh.red[1] + sh.red[2] + sh.red[3];
  float tq = sh.red[8] + sh.red[9] + sh.red[10] + sh.red[11];
  float mu = ts * (1.0f / D2);
  float rstd = rsqrtf(tq * (1.0f / D2) - mu * mu + EPS_F);
#pragma unroll
  for (int k = 0; k < 8; ++k) {
    int idx = tid * 8 + k;
    out[(size_t)t * D2 + idx] = (y[k] - mu) * rstd * g2[idx] + b2[idx];
  }
}

__global__ __launch_bounds__(256, 4) void mega_kernel(
    const float* __restrict__ x, const float* __restrict__ g1, const float* __restrict__ b1,
    const int* __restrict__ node_idx, const int* __restrict__ sidx,
    const float* __restrict__ g2, const float* __restrict__ b2,
    unsigned* __restrict__ W8w, float* __restrict__ P, float* __restrict__ Agg,
    float* __restrict__ out) {
  cg::grid_group grid = cg::this_grid();
  __shared__ SharedT sh;
  const int gtid = blockIdx.x * BLK_C + threadIdx.x;   // 262144 threads

  for (int i = gtid; i < W_WORDS; i += GRID_C * BLK_C) W8w[i] = 0u;
  grid.sync();
  if (gtid < COMP_LEN_C * MAX_LEN_C) {
    int c = gtid / MAX_LEN_C;
    int n = sidx[gtid];
    int byteoff = n * COMP_LEN_C + c;
    atomicAdd(&W8w[byteoff >> 2], 1u << (8 * (byteoff & 3)));
  }
  grid.sync();
  phase_main(sh, blockIdx.x, x, g1, b1, node_idx, (const unsigned*)W8w, P);
  grid.sync();
  if (blockIdx.x < 512) phase_reduce(sh, blockIdx.x, P, Agg);
  grid.sync();
  if (blockIdx.x < T_DIM) phase_final(sh, blockIdx.x, Agg, g2, b2, out);
}

// ---- Fallback (non-coop), identical math.
__global__ void build_w8_kernel(const int* __restrict__ sidx, unsigned* __restrict__ W8w) {
  const int c  = blockIdx.x >> 2;
  const int jc = blockIdx.x & 3;
  const int j  = jc * 196 + threadIdx.x;
  if (j < MAX_LEN_C && threadIdx.x < 196) {
    int n = sidx[c * MAX_LEN_C + j];
    int byteoff = n * COMP_LEN_C + c;
    atomicAdd(&W8w[byteoff >> 2], 1u << (8 * (byteoff & 3)));
  }
}
__global__ __launch_bounds__(256, 4) void main_nc(
    const float* __restrict__ x, const float* __restrict__ g1, const float* __restrict__ b1,
    const int* __restrict__ node_idx, const unsigned* __restrict__ W32,
    float* __restrict__ P) {
  __shared__ SharedT sh;
  phase_main(sh, blockIdx.x, x, g1, b1, node_idx, W32, P);
}
__global__ __launch_bounds__(256) void reduce_nc(const float* __restrict__ P,
                                                float* __restrict__ Agg) {
  __shared__ SharedT sh;
  phase_reduce(sh, blockIdx.x, P, Agg);
}
__global__ __launch_bounds__(256) void final_nc(
    const float* __restrict__ Agg, const float* __restrict__ g2,
    const float* __restrict__ b2, float* __restrict__ out) {
  __shared__ SharedT sh;
  phase_final(sh, blockIdx.x, Agg, g2, b2, out);
}

extern "C" void kernel_launch(void* const* d_in, const int* in_sizes, int n_in,
                              void* d_out, int out_size, void* d_ws, size_t ws_size,
                              hipStream_t stream) {
  const float* x     = (const float*)d_in[0];
  const float* ln1_g = (const float*)d_in[1];
  const float* ln1_b = (const float*)d_in[2];
  const float* ln2_g = (const float*)d_in[3];
  const float* ln2_b = (const float*)d_in[4];
  const int* node_idx = (const int*)d_in[5];
  const int* sidx     = (const int*)d_in[6];
  float* out = (float*)d_out;

  unsigned char* ws = (unsigned char*)d_ws;
  unsigned* W8w = (unsigned*)ws;
  float* P   = (float*)(ws + P_OFF);
  float* Agg = (float*)(ws + AGG_OFF);

  int maxActive = 0;
  hipError_t occ = hipOccupancyMaxActiveBlocksPerMultiprocessor(
      &maxActive, (const void*)mega_kernel, BLK_C, 0);
  bool coop = (occ == hipSuccess) && (maxActive >= 4);   // 1024 blocks / 256 CU

  if (coop) {
    void* args[] = {(void*)&x, (void*)&ln1_g, (void*)&ln1_b, (void*)&node_idx,
                    (void*)&sidx, (void*)&ln2_g, (void*)&ln2_b,
                    (void*)&W8w, (void*)&P, (void*)&Agg, (void*)&out};
    hipError_t e = hipLaunchCooperativeKernel((void*)mega_kernel, dim3(GRID_C),
                                              dim3(BLK_C), args, 0, stream);
    if (e == hipSuccess) return;
  }

  hipMemsetAsync(W8w, 0, W8_BYTES, stream);
  build_w8_kernel<<<COMP_LEN_C * 4, 256, 0, stream>>>(sidx, W8w);
  main_nc<<<GRID_C, BLK_C, 0, stream>>>(x, ln1_g, ln1_b, node_idx,
                                        (const unsigned*)W8w, P);
  reduce_nc<<<512, 256, 0, stream>>>(P, Agg);
  final_nc<<<T_DIM, 256, 0, stream>>>(Agg, ln2_g, ln2_b, out);
}